// Round 4
// baseline (542.802 us; speedup 1.0000x reference)
//
#include <hip/hip_runtime.h>

// Problem geometry (compile-time constants from the reference).
static constexpr int XD = 400;
static constexpr int YD = 400;
static constexpr int ZD = 8;
static constexpr int CD = 64;                          // channels per cell
static constexpr int NCELLS = XD * YD * ZD;            // 1,280,000 cells
static constexpr long long CELL_F4  = CD / 4;          // 16 float4 per cell row
static constexpr long long TOTAL_F4 = (long long)NCELLS * CELL_F4;  // 20.48M

// Native clang vector type — required by __builtin_nontemporal_load/store
// (HIP_vector_type<float,4> is a struct and is rejected).
typedef float vfloat4 __attribute__((ext_vector_type(4)));

// 1) winner[cell] = -1 (explicit init; ~5 MB, ~2 us).
__global__ void init_winner_kernel(int* __restrict__ w, int n) {
    int i = blockIdx.x * blockDim.x + threadIdx.x;
    if (i < n) w[i] = -1;
}

// 2) last-write-wins: highest update index claims the cell.
//    (XLA .at[].set applies updates in order; last duplicate wins.)
__global__ void winner_kernel(const int* __restrict__ idx,
                              int* __restrict__ w, int n) {
    int i = blockIdx.x * blockDim.x + threadIdx.x;
    if (i >= n) return;
    int ix = idx[3 * i + 0];
    int iy = idx[3 * i + 1];
    int iz = idx[3 * i + 2];
    int cell = (ix * YD + iy) * ZD + iz;
    atomicMax(&w[cell], i);
}

// 3) merged copy+scatter, grid-stride, nontemporal streaming.
//    16 threads own one cell row (64 floats); source row selected per cell:
//    winning pixels row if the cell was hit, else the voxel row.
//    Streamed data (vox/pixels/out) bypasses cache (read-once/write-once);
//    only the 5 MB winner array uses the cache hierarchy (16x reuse).
__global__ void __launch_bounds__(256)
merge_kernel(const vfloat4* __restrict__ vox,
             const vfloat4* __restrict__ pixels,
             const int* __restrict__ w,
             vfloat4* __restrict__ out) {
    long long stride = (long long)gridDim.x * blockDim.x;
    for (long long t = (long long)blockIdx.x * blockDim.x + threadIdx.x;
         t < TOTAL_F4; t += stride) {
        int cell = (int)(t >> 4);          // 16 threads per cell row
        int c    = (int)(t & 15);
        int win  = w[cell];                // cached (reused by 16 threads, L2-hot)
        const vfloat4* src = (win >= 0) ? (pixels + (long long)win * CELL_F4)
                                        : (vox    + (long long)cell * CELL_F4);
        vfloat4 v = __builtin_nontemporal_load(&src[c]);
        __builtin_nontemporal_store(v, &out[t]);
    }
}

extern "C" void kernel_launch(void* const* d_in, const int* in_sizes, int n_in,
                              void* d_out, int out_size, void* d_ws, size_t ws_size,
                              hipStream_t stream) {
    const vfloat4* voxel  = (const vfloat4*)d_in[0];
    const int*     sidx   = (const int*)d_in[1];
    const vfloat4* pixels = (const vfloat4*)d_in[2];
    vfloat4*       out4   = (vfloat4*)d_out;
    int*           winner = (int*)d_ws;                // 1.28M ints = 5.12 MB

    const int N = in_sizes[1] / 3;                     // 134,400 updates

    // 1) init winner array
    {
        int threads = 256;
        int blocks = (NCELLS + threads - 1) / threads;
        init_winner_kernel<<<blocks, threads, 0, stream>>>(winner, NCELLS);
    }
    // 2) resolve duplicate cells (last index wins)
    {
        int threads = 256;
        int blocks = (N + threads - 1) / threads;
        winner_kernel<<<blocks, threads, 0, stream>>>(sidx, winner, N);
    }
    // 3) merged copy+scatter: one write per output element, grid-stride
    //    (G11: ~8 blocks/CU, persistent, instead of 80k one-shot blocks)
    {
        int threads = 256;
        int blocks  = 4096;
        merge_kernel<<<blocks, threads, 0, stream>>>(voxel, pixels, winner, out4);
    }
}